// Round 2
// baseline (1144.799 us; speedup 1.0000x reference)
//
#include <hip/hip_runtime.h>
#include <hip/hip_bf16.h>

// LSTM (T=512, B=512, IN=300, H=16) + MLP head, fp32.
// Phase 1: xg = x @ W_ih^T + (b_ih+b_hh)  -> d_ws (64 MiB)
// Phase 2: sequential scan, one wave per 2 batch elements, fused MLP head.

#define T_STEPS 512
#define BATCH   512
#define K_IN    300
#define NG      64   // 4*HIDDEN
#define HID     16
#define KC      12   // k-chunk: 25 * 12 = 300, no tail
#define PF      8    // scan prefetch depth (register ring)
#define NB      2    // batch elements per wave in scan

// ---------------------------------------------------------------------------
// GEMM: one thread per row m. acc[64] fully register-resident (g-loop fully
// unrolled — R1's unroll-2 spilled it to scratch: VGPR=40, WRITE 860MB).
// W addresses wave-uniform -> scalar loads through K$.
// ---------------------------------------------------------------------------
__global__ __launch_bounds__(256, 4) void xg_gemm(
    const float* __restrict__ x,      // [T*B][300]
    const float* __restrict__ W,      // [64][300]
    const float* __restrict__ b_ih,   // [64]
    const float* __restrict__ b_hh,   // [64]
    float* __restrict__ xg)           // [T*B][64]
{
    const int m = blockIdx.x * 256 + threadIdx.x;  // 0..262143
    const float* xr = x + (size_t)m * K_IN;

    float acc[NG];
#pragma unroll
    for (int g = 0; g < NG; ++g) acc[g] = 0.f;

#pragma unroll 1
    for (int kc = 0; kc < K_IN; kc += KC) {
        float xv[KC];
#pragma unroll
        for (int j = 0; j < KC; j += 4)
            *(float4*)&xv[j] = *(const float4*)(xr + kc + j);

#pragma unroll
        for (int g = 0; g < NG; ++g) {
            const float* wr = W + g * K_IN + kc;   // uniform -> s_load
            float a = acc[g];
#pragma unroll
            for (int k = 0; k < KC; ++k)
                a = fmaf(xv[k], wr[k], a);
            acc[g] = a;
        }
    }

    float* op = xg + (size_t)m * NG;
#pragma unroll
    for (int g = 0; g < NG; g += 4) {
        float4 v;
        v.x = acc[g + 0] + b_ih[g + 0] + b_hh[g + 0];
        v.y = acc[g + 1] + b_ih[g + 1] + b_hh[g + 1];
        v.z = acc[g + 2] + b_ih[g + 2] + b_hh[g + 2];
        v.w = acc[g + 3] + b_ih[g + 3] + b_hh[g + 3];
        *(float4*)(op + g) = v;
    }
}

// ---------------------------------------------------------------------------
// Scan: one wave per NB=2 batch elements; lane r owns gate r of both.
// Two independent recurrence chains per wave -> ILP hides VALU/trans/shfl
// latency. xg prefetched PF=8 steps ahead in registers (covers ~900cyc HBM).
// h broadcast via v_readlane -> SGPRs. Fast rcp for sigmoid/tanh.
// ---------------------------------------------------------------------------
__global__ __launch_bounds__(64) void lstm_scan(
    const float* __restrict__ xg,    // [T][B][64], biases included
    const float* __restrict__ Whh,   // [64][16]
    const float* __restrict__ W1,    // [64][16]
    const float* __restrict__ b1,    // [64]
    const float* __restrict__ W2,    // [64]
    const float* __restrict__ b2,    // [1]
    float* __restrict__ out)         // [B]
{
    const int bb = blockIdx.x * NB;
    const int r  = threadIdx.x;         // gate 0..63
    const int jj = r & 15;              // hidden unit this lane updates
    const bool isg = ((r >> 4) == 2);   // lanes 32..47: g-gate (tanh)

    float whh[HID];
#pragma unroll
    for (int j = 0; j < HID; j += 4)
        *(float4*)&whh[j] = *(const float4*)(Whh + r * HID + j);

    float c0 = 0.f, c1 = 0.f;
    float hs0[HID], hs1[HID];
#pragma unroll
    for (int j = 0; j < HID; ++j) { hs0[j] = 0.f; hs1[j] = 0.f; }

    const size_t tstride = (size_t)BATCH * NG;
    const float* p0 = xg + (size_t)bb * NG + r;
    const float* p1 = p0 + NG;

    float buf0[PF], buf1[PF];
#pragma unroll
    for (int i = 0; i < PF; ++i) {
        buf0[i] = p0[i * tstride];
        buf1[i] = p1[i * tstride];
    }

#pragma unroll 1
    for (int tt = 0; tt < T_STEPS; tt += PF) {
#pragma unroll
        for (int u = 0; u < PF; ++u) {
            const int t = tt + u;
            const float cur0 = buf0[u], cur1 = buf1[u];
            if (t + PF < T_STEPS) {
                buf0[u] = p0[(size_t)(t + PF) * tstride];
                buf1[u] = p1[(size_t)(t + PF) * tstride];
            }

            // gate pre-activations for both chains (hs* live in SGPRs)
            float a0 = cur0, a1 = 0.f, d0 = cur1, d1 = 0.f;
#pragma unroll
            for (int j = 0; j < HID; j += 2) {
                a0 = fmaf(whh[j],     hs0[j],     a0);
                a1 = fmaf(whh[j + 1], hs0[j + 1], a1);
                d0 = fmaf(whh[j],     hs1[j],     d0);
                d1 = fmaf(whh[j + 1], hs1[j + 1], d1);
            }
            const float gp0 = a0 + a1, gp1 = d0 + d1;

            // sigmoid for i/f/o lanes; tanh = 2*sigmoid(2x)-1 for g lanes
            const float e0 = isg ? 2.f * gp0 : gp0;
            const float e1 = isg ? 2.f * gp1 : gp1;
            const float sg0 = __builtin_amdgcn_rcpf(1.f + __expf(-e0));
            const float sg1 = __builtin_amdgcn_rcpf(1.f + __expf(-e1));
            const float act0 = isg ? fmaf(2.f, sg0, -1.f) : sg0;
            const float act1 = isg ? fmaf(2.f, sg1, -1.f) : sg1;

            // gather i,f,g,o for hidden unit jj (independent bpermutes)
            const float iv0 = __shfl(act0, jj,      64);
            const float fv0 = __shfl(act0, jj + 16, 64);
            const float gv0 = __shfl(act0, jj + 32, 64);
            const float ov0 = __shfl(act0, jj + 48, 64);
            const float iv1 = __shfl(act1, jj,      64);
            const float fv1 = __shfl(act1, jj + 16, 64);
            const float gv1 = __shfl(act1, jj + 32, 64);
            const float ov1 = __shfl(act1, jj + 48, 64);

            c0 = fmaf(fv0, c0, iv0 * gv0);
            c1 = fmaf(fv1, c1, iv1 * gv1);
            const float sc0 = __builtin_amdgcn_rcpf(1.f + __expf(-2.f * c0));
            const float sc1 = __builtin_amdgcn_rcpf(1.f + __expf(-2.f * c1));
            const float h0 = ov0 * fmaf(2.f, sc0, -1.f);
            const float h1 = ov1 * fmaf(2.f, sc1, -1.f);

            // broadcast h[0..15] (lanes 0..15) into SGPRs for next step
#pragma unroll
            for (int j = 0; j < HID; ++j) {
                hs0[j] = __int_as_float(__builtin_amdgcn_readlane(__float_as_int(h0), j));
                hs1[j] = __int_as_float(__builtin_amdgcn_readlane(__float_as_int(h1), j));
            }
        }
    }

    // ---- MLP head: z = relu(h @ W1^T + b1); out = 4*sigmoid(z @ W2^T + b2)
    float w1r[HID];
#pragma unroll
    for (int j = 0; j < HID; j += 4)
        *(float4*)&w1r[j] = *(const float4*)(W1 + r * HID + j);
    float z0 = b1[r], z1 = z0;
#pragma unroll
    for (int j = 0; j < HID; ++j) {
        z0 = fmaf(w1r[j], hs0[j], z0);
        z1 = fmaf(w1r[j], hs1[j], z1);
    }
    z0 = fmaxf(z0, 0.f);
    z1 = fmaxf(z1, 0.f);

    const float w2 = W2[r];
    float y0 = z0 * w2, y1 = z1 * w2;
#pragma unroll
    for (int off = 32; off; off >>= 1) {
        y0 += __shfl_xor(y0, off, 64);
        y1 += __shfl_xor(y1, off, 64);
    }

    if (r == 0) {
        const float bias = b2[0];
        out[bb + 0] = 4.f * __builtin_amdgcn_rcpf(1.f + __expf(-(y0 + bias)));
        out[bb + 1] = 4.f * __builtin_amdgcn_rcpf(1.f + __expf(-(y1 + bias)));
    }
}

extern "C" void kernel_launch(void* const* d_in, const int* in_sizes, int n_in,
                              void* d_out, int out_size, void* d_ws, size_t ws_size,
                              hipStream_t stream) {
    const float* x    = (const float*)d_in[0];
    const float* W_ih = (const float*)d_in[1];
    const float* W_hh = (const float*)d_in[2];
    const float* b_ih = (const float*)d_in[3];
    const float* b_hh = (const float*)d_in[4];
    const float* W1   = (const float*)d_in[5];
    const float* b1   = (const float*)d_in[6];
    const float* W2   = (const float*)d_in[7];
    const float* b2   = (const float*)d_in[8];
    float* out = (float*)d_out;
    float* xg  = (float*)d_ws;   // T*B*64*4 = 64 MiB

    xg_gemm<<<dim3(T_STEPS * BATCH / 256), dim3(256), 0, stream>>>(x, W_ih, b_ih, b_hh, xg);
    lstm_scan<<<dim3(BATCH / NB), dim3(64), 0, stream>>>(xg, W_hh, W1, b1, W2, b2, out);
}

// Round 3
// 724.323 us; speedup vs baseline: 1.5805x; 1.5805x over previous
//
#include <hip/hip_runtime.h>
#include <hip/hip_bf16.h>

// LSTM (T=512, B=512, IN=300, H=16) + MLP head, fp32.
// Phase 1: xg[b][t][g] = x[t][b][:] . W_ih[g][:] + (b_ih+b_hh)[g]   -> d_ws
//          (note scan-friendly [B][T][64] layout)
// Phase 2: sequential scan, one wave per batch element, deep register
//          prefetch ring, fused MLP head.

#define T_STEPS 512
#define BATCH   512
#define K_IN    300
#define NG      64   // 4*HIDDEN
#define HID     16
#define KC      12   // k-chunk: 25 * 12 = 300, no tail
#define DPF     16   // scan prefetch distance (register ring)

// ---------------------------------------------------------------------------
// GEMM: block = 256 threads = 4 waves over 64 consecutive rows.
// Wave w computes gates [16w, 16w+16) for its lane's row: acc[16] only
// (R1/R2's 64-acc-per-thread design spilled: VGPR=52, WRITE 237MB).
// Gate base is wave-uniform (readfirstlane) -> W reads are s_load broadcast.
// The 4 waves re-read the same x lines back-to-back -> L1/L2 hits.
// ---------------------------------------------------------------------------
__global__ __launch_bounds__(256, 4) void xg_gemm(
    const float* __restrict__ x,      // [T*B][300]
    const float* __restrict__ W,      // [64][300]
    const float* __restrict__ b_ih,   // [64]
    const float* __restrict__ b_hh,   // [64]
    float* __restrict__ xg)           // [B][T][64]
{
    const int lane = threadIdx.x & 63;
    const int wgrp = __builtin_amdgcn_readfirstlane(threadIdx.x >> 6); // 0..3
    const int g0   = wgrp * 16;
    const int row  = blockIdx.x * 64 + lane;       // m = t*B + b
    const float* xr = x + (size_t)row * K_IN;

    float acc[16];
#pragma unroll
    for (int g = 0; g < 16; ++g) acc[g] = 0.f;

#pragma unroll 1
    for (int kc = 0; kc < K_IN; kc += KC) {
        float xv[KC];
#pragma unroll
        for (int j = 0; j < KC; j += 4)
            *(float4*)&xv[j] = *(const float4*)(xr + kc + j);

#pragma unroll
        for (int g = 0; g < 16; ++g) {
            const float* wr = W + (size_t)(g0 + g) * K_IN + kc;  // uniform -> s_load
            float a = acc[g];
#pragma unroll
            for (int k = 0; k < KC; ++k)
                a = fmaf(xv[k], wr[k], a);
            acc[g] = a;
        }
    }

    // epilogue: add biases, store to [B][T][64]
    const int t = row >> 9;          // row / BATCH
    const int b = row & (BATCH - 1);
    float* op = xg + ((size_t)b * T_STEPS + t) * NG + g0;
#pragma unroll
    for (int g = 0; g < 16; g += 4) {
        float4 v;
        v.x = acc[g + 0] + b_ih[g0 + g + 0] + b_hh[g0 + g + 0];
        v.y = acc[g + 1] + b_ih[g0 + g + 1] + b_hh[g0 + g + 1];
        v.z = acc[g + 2] + b_ih[g0 + g + 2] + b_hh[g0 + g + 2];
        v.w = acc[g + 3] + b_ih[g0 + g + 3] + b_hh[g0 + g + 3];
        *(float4*)(op + g) = v;
    }
}

// ---------------------------------------------------------------------------
// Scan: one wave per batch element (512 waves); lane r owns gate r.
// xg in [B][T][64] -> sequential 256B/step stream per wave.
// Register prefetch ring of depth 16, UNCONDITIONAL clamped loads so 16
// loads stay in flight (R2's conditional ring collapsed to distance ~1).
// h broadcast via v_readlane -> SGPRs. rcp-based sigmoid/tanh.
// ---------------------------------------------------------------------------
__global__ __launch_bounds__(64) void lstm_scan(
    const float* __restrict__ xg,    // [B][T][64], biases included
    const float* __restrict__ Whh,   // [64][16]
    const float* __restrict__ W1,    // [64][16]
    const float* __restrict__ b1,    // [64]
    const float* __restrict__ W2,    // [64]
    const float* __restrict__ b2,    // [1]
    float* __restrict__ out)         // [B]
{
    const int b  = blockIdx.x;
    const int r  = threadIdx.x;         // gate 0..63
    const int jj = r & 15;              // hidden unit this lane updates
    const bool isg = ((r >> 4) == 2);   // lanes 32..47: g-gate (tanh)

    float whh[HID];
#pragma unroll
    for (int j = 0; j < HID; j += 4)
        *(float4*)&whh[j] = *(const float4*)(Whh + r * HID + j);

    float c = 0.f;
    float hs[HID];
#pragma unroll
    for (int j = 0; j < HID; ++j) hs[j] = 0.f;

    const float* xgb = xg + (size_t)b * T_STEPS * NG + r;   // step stride = NG

    float buf[DPF];
#pragma unroll
    for (int i = 0; i < DPF; ++i)
        buf[i] = xgb[(size_t)i * NG];

#pragma unroll 1
    for (int tt = 0; tt < T_STEPS; tt += DPF) {
#pragma unroll
        for (int u = 0; u < DPF; ++u) {
            const int t = tt + u;
            const float cur = buf[u];
            // unconditional clamped prefetch: keeps 16 loads in flight
            int tl = t + DPF;
            if (tl > T_STEPS - 1) tl = T_STEPS - 1;   // uniform select, no branch
            buf[u] = xgb[(size_t)tl * NG];

            // gate pre-activation: cur + W_hh[r,:].h  (hs live in SGPRs)
            float a0 = cur, a1 = 0.f, a2 = 0.f, a3 = 0.f;
#pragma unroll
            for (int j = 0; j < HID; j += 4) {
                a0 = fmaf(whh[j + 0], hs[j + 0], a0);
                a1 = fmaf(whh[j + 1], hs[j + 1], a1);
                a2 = fmaf(whh[j + 2], hs[j + 2], a2);
                a3 = fmaf(whh[j + 3], hs[j + 3], a3);
            }
            const float gp = (a0 + a1) + (a2 + a3);

            // sigmoid for i/f/o lanes; tanh = 2*sigmoid(2x)-1 for g lanes
            const float e   = isg ? 2.f * gp : gp;
            const float sg  = __builtin_amdgcn_rcpf(1.f + __expf(-e));
            const float act = isg ? fmaf(2.f, sg, -1.f) : sg;

            // gather i,f,g,o for hidden unit jj
            const float iv = __shfl(act, jj,      64);
            const float fv = __shfl(act, jj + 16, 64);
            const float gv = __shfl(act, jj + 32, 64);
            const float ov = __shfl(act, jj + 48, 64);

            c = fmaf(fv, c, iv * gv);
            const float sc = __builtin_amdgcn_rcpf(1.f + __expf(-2.f * c));
            const float h  = ov * fmaf(2.f, sc, -1.f);

            // broadcast h[0..15] (lanes 0..15) into SGPRs for next step
#pragma unroll
            for (int j = 0; j < HID; ++j)
                hs[j] = __int_as_float(__builtin_amdgcn_readlane(__float_as_int(h), j));
        }
    }

    // ---- MLP head: z = relu(h @ W1^T + b1); out = 4*sigmoid(z @ W2^T + b2)
    float w1r[HID];
#pragma unroll
    for (int j = 0; j < HID; j += 4)
        *(float4*)&w1r[j] = *(const float4*)(W1 + r * HID + j);
    float z = b1[r];
#pragma unroll
    for (int j = 0; j < HID; ++j) z = fmaf(w1r[j], hs[j], z);
    z = fmaxf(z, 0.f);

    float y = z * W2[r];
#pragma unroll
    for (int off = 32; off; off >>= 1) y += __shfl_xor(y, off, 64);

    if (r == 0) out[b] = 4.f * __builtin_amdgcn_rcpf(1.f + __expf(-(y + b2[0])));
}

extern "C" void kernel_launch(void* const* d_in, const int* in_sizes, int n_in,
                              void* d_out, int out_size, void* d_ws, size_t ws_size,
                              hipStream_t stream) {
    const float* x    = (const float*)d_in[0];
    const float* W_ih = (const float*)d_in[1];
    const float* W_hh = (const float*)d_in[2];
    const float* b_ih = (const float*)d_in[3];
    const float* b_hh = (const float*)d_in[4];
    const float* W1   = (const float*)d_in[5];
    const float* b1   = (const float*)d_in[6];
    const float* W2   = (const float*)d_in[7];
    const float* b2   = (const float*)d_in[8];
    float* out = (float*)d_out;
    float* xg  = (float*)d_ws;   // [B][T][64] = 64 MiB

    xg_gemm<<<dim3(T_STEPS * BATCH / 64), dim3(256), 0, stream>>>(x, W_ih, b_ih, b_hh, xg);
    lstm_scan<<<dim3(BATCH), dim3(64), 0, stream>>>(xg, W_hh, W1, b1, W2, b2, out);
}

// Round 4
// 707.422 us; speedup vs baseline: 1.6183x; 1.0239x over previous
//
#include <hip/hip_runtime.h>
#include <hip/hip_bf16.h>

// LSTM (T=512, B=512, IN=300, H=16) + MLP head, fp32 in/out.
// Phase 1: xg[b][t][g] = x[t*B+b][:] . W_ih[g][:] + (b_ih+b_hh)[g]
//          via bf16 MFMA 16x16x32, direct-from-global fragments (no LDS).
// Phase 2: scan with lane = (batch q, hidden j): 4 batches/wave, in-lane
//          gate math, h distributed by 16 parallel ds_bpermute.

#define T_STEPS 512
#define BATCH   512
#define K_IN    300
#define NG      64   // 4*HIDDEN
#define HID     16
#define DPF     4    // scan prefetch ring depth (per gate stream)

typedef float  f32x4  __attribute__((ext_vector_type(4)));
typedef float  f32x8  __attribute__((ext_vector_type(8)));
typedef __bf16 bf16x8 __attribute__((ext_vector_type(8)));

static __device__ __forceinline__ bf16x8 cvt8(float4 lo, float4 hi) {
    f32x8 t;
    t[0] = lo.x; t[1] = lo.y; t[2] = lo.z; t[3] = lo.w;
    t[4] = hi.x; t[5] = hi.y; t[6] = hi.z; t[7] = hi.w;
    return __builtin_convertvector(t, bf16x8);
}

// ---------------------------------------------------------------------------
// MFMA GEMM: block = 4 waves x 16 rows = 64 rows. Wave computes its 16-row
// strip x all 64 gates (4 n-tiles, f32x4 acc each). A-frag: lane(m=lane&15,
// quad=lane>>4) reads x[row][k0+quad*8 .. +8] = 2 float4 -> cvt bf16.
// B-frag mirrors it on W rows (n=lane&15). K = 9 full 32-tiles + masked tail.
// ---------------------------------------------------------------------------
__global__ __launch_bounds__(256) void xg_gemm(
    const float* __restrict__ x,      // [T*B][300]
    const float* __restrict__ W,      // [64][300]
    const float* __restrict__ b_ih,   // [64]
    const float* __restrict__ b_hh,   // [64]
    float* __restrict__ xg)           // [B][T][64]
{
    const int lane = threadIdx.x & 63;
    const int wv   = threadIdx.x >> 6;
    const int m16  = lane & 15;
    const int quad = lane >> 4;
    const int row0 = blockIdx.x * 64 + wv * 16;

    const float* xr = x + (size_t)(row0 + m16) * K_IN;
    const float* wr = W + (size_t)m16 * K_IN;

    f32x4 acc[4];
#pragma unroll
    for (int nt = 0; nt < 4; ++nt) acc[nt] = (f32x4){0.f, 0.f, 0.f, 0.f};

#pragma unroll 1
    for (int ks = 0; ks < 9; ++ks) {
        const int k = ks * 32 + quad * 8;
        const bf16x8 af = cvt8(*(const float4*)(xr + k),
                               *(const float4*)(xr + k + 4));
#pragma unroll
        for (int nt = 0; nt < 4; ++nt) {
            const float* wp = wr + (size_t)nt * 16 * K_IN + k;
            const bf16x8 bf = cvt8(*(const float4*)(wp),
                                   *(const float4*)(wp + 4));
            acc[nt] = __builtin_amdgcn_mfma_f32_16x16x32_bf16(af, bf, acc[nt], 0, 0, 0);
        }
    }
    {   // tail tile k0=288: cols 300..319 must be zero (mask per quad)
        const int kb = 288 + quad * 8;
        const float4 z4 = {0.f, 0.f, 0.f, 0.f};
        const float4 alo = (kb + 3 < K_IN) ? *(const float4*)(xr + kb)     : z4;
        const float4 ahi = (kb + 7 < K_IN) ? *(const float4*)(xr + kb + 4) : z4;
        const bf16x8 af = cvt8(alo, ahi);
#pragma unroll
        for (int nt = 0; nt < 4; ++nt) {
            const float* wp = wr + (size_t)nt * 16 * K_IN + kb;
            const float4 blo = (kb + 3 < K_IN) ? *(const float4*)(wp)     : z4;
            const float4 bhi = (kb + 7 < K_IN) ? *(const float4*)(wp + 4) : z4;
            const bf16x8 bf = cvt8(blo, bhi);
            acc[nt] = __builtin_amdgcn_mfma_f32_16x16x32_bf16(af, bf, acc[nt], 0, 0, 0);
        }
    }

    // epilogue: C/D layout col=lane&15, row=quad*4+reg. Block rows share t.
    float bias[4];
#pragma unroll
    for (int nt = 0; nt < 4; ++nt)
        bias[nt] = b_ih[nt * 16 + m16] + b_hh[nt * 16 + m16];

#pragma unroll
    for (int reg = 0; reg < 4; ++reg) {
        const int R = row0 + quad * 4 + reg;   // = t*512 + b
        const int t = R >> 9;
        const int b = R & (BATCH - 1);
        float* op = xg + ((size_t)b * T_STEPS + t) * NG + m16;
        op[0]  = acc[0][reg] + bias[0];
        op[16] = acc[1][reg] + bias[1];
        op[32] = acc[2][reg] + bias[2];
        op[48] = acc[3][reg] + bias[3];
    }
}

// ---------------------------------------------------------------------------
// Scan: lane = (q=lane>>4, j=lane&15): batch blockIdx*4+q, hidden unit j.
// Per lane: all 4 W_hh gate rows (64 VGPR), i/f/g/o dots + c/h in-lane.
// h distributed via 16 parallel ds_bpermute from the lane's 16-group.
// xg [B][T][64]: 4 coalesced dword loads/step/lane, DPF=4 clamped ring.
// ---------------------------------------------------------------------------
__global__ __launch_bounds__(64) void lstm_scan(
    const float* __restrict__ xg,    // [B][T][64], biases included
    const float* __restrict__ Whh,   // [64][16]
    const float* __restrict__ W1,    // [64][16]
    const float* __restrict__ b1,    // [64]
    const float* __restrict__ W2,    // [64]
    const float* __restrict__ b2,    // [1]
    float* __restrict__ out)         // [B]
{
    const int lane = threadIdx.x;
    const int q = lane >> 4;         // batch sub-index 0..3
    const int j = lane & 15;         // hidden unit
    const int batch = blockIdx.x * 4 + q;
    const int pbase = (lane & 48) << 2;   // ds_bpermute group base (bytes)

    // W_hh rows j (i), j+16 (f), j+32 (g), j+48 (o)
    float wi[HID], wf[HID], wg[HID], wo[HID];
#pragma unroll
    for (int k = 0; k < HID; k += 4) {
        *(float4*)&wi[k] = *(const float4*)(Whh + (j     ) * HID + k);
        *(float4*)&wf[k] = *(const float4*)(Whh + (j + 16) * HID + k);
        *(float4*)&wg[k] = *(const float4*)(Whh + (j + 32) * HID + k);
        *(float4*)&wo[k] = *(const float4*)(Whh + (j + 48) * HID + k);
    }

    float c = 0.f;
    float hb[HID];
#pragma unroll
    for (int k = 0; k < HID; ++k) hb[k] = 0.f;

    const float* xgb = xg + (size_t)batch * T_STEPS * NG + j;  // t-stride 64

    float bi[DPF], bfr[DPF], bg[DPF], bo[DPF];
#pragma unroll
    for (int u = 0; u < DPF; ++u) {
        const float* pl = xgb + (size_t)u * NG;
        bi[u] = pl[0]; bfr[u] = pl[16]; bg[u] = pl[32]; bo[u] = pl[48];
    }

#pragma unroll 1
    for (int tt = 0; tt < T_STEPS; tt += DPF) {
#pragma unroll
        for (int u = 0; u < DPF; ++u) {
            const int t = tt + u;
            const float ci = bi[u], cf = bfr[u], cg = bg[u], co = bo[u];
            int tl = t + DPF; if (tl > T_STEPS - 1) tl = T_STEPS - 1;
            const float* pl = xgb + (size_t)tl * NG;
            bi[u] = pl[0]; bfr[u] = pl[16]; bg[u] = pl[32]; bo[u] = pl[48];

            // four in-lane dots over the group's h (hb)
            float si = ci, sf = cf, sg = cg, so = co;
#pragma unroll
            for (int k = 0; k < HID; ++k) {
                si = fmaf(wi[k], hb[k], si);
                sf = fmaf(wf[k], hb[k], sf);
                sg = fmaf(wg[k], hb[k], sg);
                so = fmaf(wo[k], hb[k], so);
            }

            const float ai = __builtin_amdgcn_rcpf(1.f + __expf(-si));
            const float af = __builtin_amdgcn_rcpf(1.f + __expf(-sf));
            const float ao = __builtin_amdgcn_rcpf(1.f + __expf(-so));
            const float tg = fmaf(2.f, __builtin_amdgcn_rcpf(1.f + __expf(-2.f * sg)), -1.f);

            c = fmaf(af, c, ai * tg);
            const float th = fmaf(2.f, __builtin_amdgcn_rcpf(1.f + __expf(-2.f * c)), -1.f);
            const float h = ao * th;

            // distribute h across the 16-lane group (parallel bpermutes)
            const int hI = __float_as_int(h);
#pragma unroll
            for (int k = 0; k < HID; ++k)
                hb[k] = __int_as_float(__builtin_amdgcn_ds_bpermute(pbase + 4 * k, hI));
        }
    }

    // ---- fused MLP head: lane handles z rows {j, j+16, j+32, j+48}
    float y = 0.f;
#pragma unroll
    for (int u4 = 0; u4 < 4; ++u4) {
        const int u = u4 * 16 + j;
        float z = b1[u];
#pragma unroll
        for (int k = 0; k < HID; ++k)
            z = fmaf(W1[u * HID + k], hb[k], z);
        z = fmaxf(z, 0.f);
        y = fmaf(z, W2[u], y);
    }
    // reduce within the 16-lane group
#pragma unroll
    for (int m = 8; m; m >>= 1) y += __shfl_xor(y, m, 64);

    if (j == 0)
        out[batch] = 4.f * __builtin_amdgcn_rcpf(1.f + __expf(-(y + b2[0])));
}

extern "C" void kernel_launch(void* const* d_in, const int* in_sizes, int n_in,
                              void* d_out, int out_size, void* d_ws, size_t ws_size,
                              hipStream_t stream) {
    const float* x    = (const float*)d_in[0];
    const float* W_ih = (const float*)d_in[1];
    const float* W_hh = (const float*)d_in[2];
    const float* b_ih = (const float*)d_in[3];
    const float* b_hh = (const float*)d_in[4];
    const float* W1   = (const float*)d_in[5];
    const float* b1   = (const float*)d_in[6];
    const float* W2   = (const float*)d_in[7];
    const float* b2   = (const float*)d_in[8];
    float* out = (float*)d_out;
    float* xg  = (float*)d_ws;   // [B][T][64] = 64 MiB

    xg_gemm<<<dim3(T_STEPS * BATCH / 64), dim3(256), 0, stream>>>(x, W_ih, b_ih, b_hh, xg);
    lstm_scan<<<dim3(BATCH / 4), dim3(64), 0, stream>>>(xg, W_hh, W1, b1, W2, b2, out);
}